// Round 2
// baseline (5669.381 us; speedup 1.0000x reference)
//
#include <hip/hip_runtime.h>
#include <hip/hip_bf16.h>

// Problem constants (from reference)
#define N_PFAS 20000
#define N_GW   100000
#define N_SW   20000
// D_IN = 64, D_OUT = 128

// ---------------------------------------------------------------------------
// Edge scatter: 16 threads per edge, each handles 4 features (16B f32 load).
// agg[dst] += x_src[src] (f32 HW atomics), cnt[dst] += 1.
// ---------------------------------------------------------------------------
__global__ void scatter_kernel(const float* __restrict__ x,
                               const int* __restrict__ src,
                               const int* __restrict__ dst,
                               float* __restrict__ agg,
                               int* __restrict__ cnt,
                               int E)
{
    int total = E * 16;
    for (int idx = blockIdx.x * blockDim.x + threadIdx.x; idx < total;
         idx += gridDim.x * blockDim.x) {
        int e = idx >> 4;
        int q = (idx & 15) << 2;
        int s = src[e];
        int d = dst[e];
        float4 xv = *(const float4*)(x + s * 64 + q);
        float* a = agg + d * 64 + q;
        unsafeAtomicAdd(a + 0, xv.x);
        unsafeAtomicAdd(a + 1, xv.y);
        unsafeAtomicAdd(a + 2, xv.z);
        unsafeAtomicAdd(a + 3, xv.w);
        if ((idx & 15) == 0) atomicAdd(cnt + d, 1);
    }
}

// ---------------------------------------------------------------------------
// GW / SW nodes: h = relu(mean@Wl + x@Wr + b); out = prelu(h . W_lin + b_lin)
// One wave per node; lane l computes h[l] and h[l+64].
// Weights staged in LDS as f32 pairs (j, j+64): 2 x 32 KiB = 64 KiB.
// ---------------------------------------------------------------------------
__global__ void head_kernel(const float* __restrict__ x,
                            const float* __restrict__ agg,
                            const int* __restrict__ cnt,
                            const float* __restrict__ Wl,
                            const float* __restrict__ Wr,
                            const float* __restrict__ b,
                            const float* __restrict__ Wlin,
                            const float* __restrict__ b_lin,
                            const float* __restrict__ alpha,
                            float* __restrict__ out,
                            int N)
{
    __shared__ float2 sWl[64 * 64];   // 32 KiB
    __shared__ float2 sWr[64 * 64];   // 32 KiB
    for (int i = threadIdx.x; i < 64 * 64; i += blockDim.x) {
        int k = i >> 6, l = i & 63;
        sWl[i] = make_float2(Wl[k * 128 + l], Wl[k * 128 + l + 64]);
        sWr[i] = make_float2(Wr[k * 128 + l], Wr[k * 128 + l + 64]);
    }
    __syncthreads();

    int lane = threadIdx.x & 63;
    int wid  = threadIdx.x >> 6;
    float wl0 = Wlin[lane];
    float wl1 = Wlin[lane + 64];
    float bb0 = b[lane];
    float bb1 = b[lane + 64];
    float blin = b_lin[0];
    float al   = alpha[0];

    int wavesPerBlock = blockDim.x >> 6;
    int nwaves = wavesPerBlock * gridDim.x;
    for (int node = blockIdx.x * wavesPerBlock + wid; node < N; node += nwaves) {
        int c = cnt[node];
        float inv = 1.0f / (float)(c > 1 ? c : 1);
        float m  = agg[node * 64 + lane] * inv;
        float xv = x[node * 64 + lane];
        float h0 = bb0, h1 = bb1;
        #pragma unroll
        for (int k = 0; k < 64; k++) {
            float mk = __shfl(m, k);
            float xk = __shfl(xv, k);
            float2 wl = sWl[k * 64 + lane];
            float2 wr = sWr[k * 64 + lane];
            h0 += mk * wl.x + xk * wr.x;
            h1 += mk * wl.y + xk * wr.y;
        }
        h0 = fmaxf(h0, 0.0f);
        h1 = fmaxf(h1, 0.0f);
        float t = h0 * wl0 + h1 * wl1;
        #pragma unroll
        for (int off = 32; off > 0; off >>= 1) t += __shfl_down(t, off);
        if (lane == 0) {
            float y = t + blin;
            y = y > 0.0f ? y : al * y;
            out[node] = y;
        }
    }
}

// ---------------------------------------------------------------------------
// PFAS nodes: h = relu(mean_gp@Wl_gp + x@(Wr_gp+Wr_sp) + mean_sp@Wl_sp + b_gp+b_sp)
// Blocks specialize on output half (blockIdx & 1 -> columns [half, half+64)).
// LDS: 3 x 16 KiB f32 weight slices = 48 KiB.
// ---------------------------------------------------------------------------
__global__ void pfas_kernel(const float* __restrict__ x,
                            const float* __restrict__ aggGP,
                            const int* __restrict__ cntGP,
                            const float* __restrict__ aggSP,
                            const int* __restrict__ cntSP,
                            const float* __restrict__ WlGP,
                            const float* __restrict__ WrGP,
                            const float* __restrict__ bGP,
                            const float* __restrict__ WlSP,
                            const float* __restrict__ WrSP,
                            const float* __restrict__ bSP,
                            float* __restrict__ out,
                            int N)
{
    __shared__ float sWlGP[64 * 64];  // 16 KiB
    __shared__ float sWlSP[64 * 64];  // 16 KiB
    __shared__ float sWr[64 * 64];    // 16 KiB  (Wr_gp + Wr_sp combined)
    int half = (blockIdx.x & 1) * 64;
    for (int i = threadIdx.x; i < 64 * 64; i += blockDim.x) {
        int k = i >> 6, l = i & 63;
        sWlGP[i] = WlGP[k * 128 + half + l];
        sWlSP[i] = WlSP[k * 128 + half + l];
        sWr[i]   = WrGP[k * 128 + half + l] + WrSP[k * 128 + half + l];
    }
    __syncthreads();

    int lane = threadIdx.x & 63;
    int wid  = threadIdx.x >> 6;
    float bb = bGP[half + lane] + bSP[half + lane];

    int wavesPerBlock = blockDim.x >> 6;
    int halfBlocks = gridDim.x >> 1;
    int nwavesHalf = halfBlocks * wavesPerBlock;
    int wave = (blockIdx.x >> 1) * wavesPerBlock + wid;
    for (int node = wave; node < N; node += nwavesHalf) {
        int cg = cntGP[node];
        int cs = cntSP[node];
        float invg = 1.0f / (float)(cg > 1 ? cg : 1);
        float invs = 1.0f / (float)(cs > 1 ? cs : 1);
        float mg = aggGP[node * 64 + lane] * invg;
        float ms = aggSP[node * 64 + lane] * invs;
        float xv = x[node * 64 + lane];
        float h = bb;
        #pragma unroll
        for (int k = 0; k < 64; k++) {
            float mgk = __shfl(mg, k);
            float msk = __shfl(ms, k);
            float xk  = __shfl(xv, k);
            h += mgk * sWlGP[k * 64 + lane] + msk * sWlSP[k * 64 + lane]
               + xk * sWr[k * 64 + lane];
        }
        out[node * 128 + half + lane] = fmaxf(h, 0.0f);
    }
}

extern "C" void kernel_launch(void* const* d_in, const int* in_sizes, int n_in,
                              void* d_out, int out_size, void* d_ws, size_t ws_size,
                              hipStream_t stream)
{
    const float* x_pfas = (const float*)d_in[0];
    const float* x_gw   = (const float*)d_in[1];
    const float* x_sw   = (const float*)d_in[2];
    const int* pg_src = (const int*)d_in[3];
    const int* pg_dst = (const int*)d_in[4];
    const int* gp_src = (const int*)d_in[5];
    const int* gp_dst = (const int*)d_in[6];
    const int* sp_src = (const int*)d_in[7];
    const int* sp_dst = (const int*)d_in[8];
    const int* ps_src = (const int*)d_in[9];
    const int* ps_dst = (const int*)d_in[10];
    const float* Wl_pg = (const float*)d_in[11];
    const float* Wr_pg = (const float*)d_in[12];
    const float* b_pg  = (const float*)d_in[13];
    const float* Wl_gp = (const float*)d_in[14];
    const float* Wr_gp = (const float*)d_in[15];
    const float* b_gp  = (const float*)d_in[16];
    const float* Wl_sp = (const float*)d_in[17];
    const float* Wr_sp = (const float*)d_in[18];
    const float* b_sp  = (const float*)d_in[19];
    const float* Wl_ps = (const float*)d_in[20];
    const float* Wr_ps = (const float*)d_in[21];
    const float* b_ps  = (const float*)d_in[22];
    const float* W_lin = (const float*)d_in[23];
    const float* b_lin = (const float*)d_in[24];
    const float* alpha = (const float*)d_in[25];

    float* out = (float*)d_out;
    float* out_pfas = out;                                 // 20000*128
    float* out_gw   = out + (size_t)N_PFAS * 128;          // 100000
    float* out_sw   = out_gw + N_GW;                       // 20000

    // Workspace layout (f32 accumulators + int counts), zeroed every call.
    float* aggGW = (float*)d_ws;                 // 100000*64 = 6,400,000
    float* aggGP = aggGW + 6400000;              // 20000*64  = 1,280,000
    float* aggSP = aggGP + 1280000;              // 1,280,000
    float* aggPS = aggSP + 1280000;              // 1,280,000
    int*   cntGW = (int*)(aggPS + 1280000);      // 100,000
    int*   cntGP = cntGW + 100000;               // 20,000
    int*   cntSP = cntGP + 20000;                // 20,000
    int*   cntPS = cntSP + 20000;                // 20,000
    size_t zero_bytes = (size_t)(6400000 + 3 * 1280000 + 160000) * 4;  // 41.6 MB
    if (zero_bytes > ws_size) zero_bytes = ws_size;
    hipMemsetAsync(d_ws, 0, zero_bytes, stream);

    int E_PG = in_sizes[3];
    int E_GP = in_sizes[5];
    int E_SP = in_sizes[7];
    int E_PS = in_sizes[9];

    auto blocks_for = [](int E) {
        long long total = (long long)E * 16;
        long long b = (total + 255) / 256;
        return (int)(b > 8192 ? 8192 : b);
    };

    scatter_kernel<<<blocks_for(E_PG), 256, 0, stream>>>(x_pfas, pg_src, pg_dst, aggGW, cntGW, E_PG);
    scatter_kernel<<<blocks_for(E_GP), 256, 0, stream>>>(x_gw,   gp_src, gp_dst, aggGP, cntGP, E_GP);
    scatter_kernel<<<blocks_for(E_SP), 256, 0, stream>>>(x_sw,   sp_src, sp_dst, aggSP, cntSP, E_SP);
    scatter_kernel<<<blocks_for(E_PS), 256, 0, stream>>>(x_pfas, ps_src, ps_dst, aggPS, cntPS, E_PS);

    head_kernel<<<1024, 256, 0, stream>>>(x_gw, aggGW, cntGW, Wl_pg, Wr_pg, b_pg,
                                          W_lin, b_lin, alpha, out_gw, N_GW);
    head_kernel<<<512, 256, 0, stream>>>(x_sw, aggPS, cntPS, Wl_ps, Wr_ps, b_ps,
                                         W_lin, b_lin, alpha, out_sw, N_SW);
    pfas_kernel<<<1024, 256, 0, stream>>>(x_pfas, aggGP, cntGP, aggSP, cntSP,
                                          Wl_gp, Wr_gp, b_gp, Wl_sp, Wr_sp, b_sp,
                                          out_pfas, N_PFAS);
}

// Round 3
// 3718.997 us; speedup vs baseline: 1.5244x; 1.5244x over previous
//
#include <hip/hip_runtime.h>
#include <hip/hip_bf16.h>

// Problem constants (from reference)
#define N_PFAS 20000
#define N_GW   100000
#define N_SW   20000
// D_IN = 64, D_OUT = 128

typedef __attribute__((ext_vector_type(8))) short short8;   // 8 bf16 (4 VGPRs)
typedef __attribute__((ext_vector_type(4))) float f32x4;    // MFMA C/D frag

__device__ __forceinline__ unsigned short f2bf(float f) {
    union { float f; unsigned int u; } v;
    v.f = f;
    unsigned int u = v.u;
    unsigned int r = (u + 0x7fffu + ((u >> 16) & 1u)) >> 16;  // RNE
    return (unsigned short)r;
}

// ---------------------------------------------------------------------------
// Edge scatter: 16 threads per edge, each handles 4 features (16B f32 load).
// agg[dst] += x_src[src] (f32 HW atomics), cnt[dst] += 1.
// ---------------------------------------------------------------------------
__global__ void scatter_kernel(const float* __restrict__ x,
                               const int* __restrict__ src,
                               const int* __restrict__ dst,
                               float* __restrict__ agg,
                               int* __restrict__ cnt,
                               int E)
{
    int total = E * 16;
    for (int idx = blockIdx.x * blockDim.x + threadIdx.x; idx < total;
         idx += gridDim.x * blockDim.x) {
        int e = idx >> 4;
        int q = (idx & 15) << 2;
        int s = src[e];
        int d = dst[e];
        float4 xv = *(const float4*)(x + (size_t)s * 64 + q);
        float* a = agg + (size_t)d * 64 + q;
        unsafeAtomicAdd(a + 0, xv.x);
        unsafeAtomicAdd(a + 1, xv.y);
        unsafeAtomicAdd(a + 2, xv.z);
        unsafeAtomicAdd(a + 3, xv.w);
        if ((idx & 15) == 0) atomicAdd(cnt + d, 1);
    }
}

// ---------------------------------------------------------------------------
// GW / SW nodes via MFMA: C[64 nodes x 128] = [mean|x] @ [Wl;Wr] + b,
// fused relu + W_lin dot + prelu -> out[node] (scalar).
// LDS: W^T bf16 [128 col][136 k-pad] = 34 KiB, A bf16 [64][136] = 17 KiB.
// Wave w owns rows 16w..16w+15, all 8 col-tiles. 16x16x32 bf16 MFMA.
// ---------------------------------------------------------------------------
__global__ void __launch_bounds__(256)
head_mfma(const float* __restrict__ x, const float* __restrict__ agg,
          const int* __restrict__ cnt,
          const float* __restrict__ Wl, const float* __restrict__ Wr,
          const float* __restrict__ b, const float* __restrict__ Wlin,
          const float* __restrict__ b_lin, const float* __restrict__ alpha,
          float* __restrict__ out, int N)
{
    __shared__ __align__(16) unsigned short sW[128][136];
    __shared__ __align__(16) unsigned short sA[64][136];

    // Stage W^T (col-major rows of K): k<64 -> Wl, k in [64,128) -> Wr.
    for (int i = threadIdx.x; i < 64 * 128; i += 256) {
        int k = i >> 7, col = i & 127;
        sW[col][k]      = f2bf(Wl[k * 128 + col]);
        sW[col][64 + k] = f2bf(Wr[k * 128 + col]);
    }

    int lane = threadIdx.x & 63;
    int wid  = threadIdx.x >> 6;
    int c    = lane & 15;
    int quad = lane >> 4;
    float wl_c[8], b_c[8];
    #pragma unroll
    for (int t = 0; t < 8; t++) {
        wl_c[t] = Wlin[t * 16 + c];
        b_c[t]  = b[t * 16 + c];
    }
    float blin = b_lin[0], al = alpha[0];

    int ntiles = (N + 63) >> 6;
    for (int tile = blockIdx.x; tile < ntiles; tile += gridDim.x) {
        int base = tile << 6;
        __syncthreads();   // protect sA from previous iteration (and sW on iter 0)
        for (int i = threadIdx.x; i < 64 * 16; i += 256) {
            int row = i >> 4, q = (i & 15) << 2;
            int node = base + row;
            if (node < N) {
                float4 av = *(const float4*)(agg + (size_t)node * 64 + q);
                float4 xv = *(const float4*)(x + (size_t)node * 64 + q);
                int cn = cnt[node];
                float inv = 1.0f / (float)(cn > 1 ? cn : 1);
                sA[row][q + 0] = f2bf(av.x * inv);
                sA[row][q + 1] = f2bf(av.y * inv);
                sA[row][q + 2] = f2bf(av.z * inv);
                sA[row][q + 3] = f2bf(av.w * inv);
                sA[row][64 + q + 0] = f2bf(xv.x);
                sA[row][64 + q + 1] = f2bf(xv.y);
                sA[row][64 + q + 2] = f2bf(xv.z);
                sA[row][64 + q + 3] = f2bf(xv.w);
            } else {
                #pragma unroll
                for (int j = 0; j < 4; j++) {
                    sA[row][q + j] = 0;
                    sA[row][64 + q + j] = 0;
                }
            }
        }
        __syncthreads();

        f32x4 acc[8] = {};
        #pragma unroll
        for (int step = 0; step < 4; step++) {
            short8 a = *(const short8*)&sA[wid * 16 + c][step * 32 + quad * 8];
            #pragma unroll
            for (int t = 0; t < 8; t++) {
                short8 bb = *(const short8*)&sW[t * 16 + c][step * 32 + quad * 8];
                acc[t] = __builtin_amdgcn_mfma_f32_16x16x32_bf16(a, bb, acc[t], 0, 0, 0);
            }
        }

        // Epilogue: relu + dot with W_lin (cols), reduce across the 16 lanes
        // of each quad (they hold the 16 cols of each col-tile).
        float p[4] = {0.f, 0.f, 0.f, 0.f};
        #pragma unroll
        for (int t = 0; t < 8; t++) {
            #pragma unroll
            for (int r = 0; r < 4; r++) {
                float h = fmaxf(acc[t][r] + b_c[t], 0.0f);
                p[r] += h * wl_c[t];
            }
        }
        #pragma unroll
        for (int m = 1; m < 16; m <<= 1) {
            #pragma unroll
            for (int r = 0; r < 4; r++) p[r] += __shfl_xor(p[r], m);
        }
        if (c == 0) {
            #pragma unroll
            for (int r = 0; r < 4; r++) {
                int node = base + wid * 16 + quad * 4 + r;
                if (node < N) {
                    float y = p[r] + blin;
                    out[node] = y > 0.0f ? y : al * y;
                }
            }
        }
    }
}

// ---------------------------------------------------------------------------
// PFAS nodes via MFMA: C[32 x 128] = [mean_gp|mean_sp|x] @ [WlGP;WlSP;Wr_sum]
// + b_sum, relu, direct store to out (128 wide).
// LDS: W^T [128][200] = 50 KiB, A [32][200] = 12.5 KiB (total 64000 B).
// Wave w: rows (w&1)*16, col-tiles (w>>1)*4 .. +3.
// ---------------------------------------------------------------------------
__global__ void __launch_bounds__(256)
pfas_mfma(const float* __restrict__ x,
          const float* __restrict__ aggGP, const int* __restrict__ cntGP,
          const float* __restrict__ aggSP, const int* __restrict__ cntSP,
          const float* __restrict__ WlGP, const float* __restrict__ WrGP,
          const float* __restrict__ bGP,
          const float* __restrict__ WlSP, const float* __restrict__ WrSP,
          const float* __restrict__ bSP,
          float* __restrict__ out, int N)
{
    __shared__ __align__(16) unsigned short sW[128][200];
    __shared__ __align__(16) unsigned short sA[32][200];

    for (int i = threadIdx.x; i < 64 * 128; i += 256) {
        int k = i >> 7, col = i & 127;
        sW[col][k]       = f2bf(WlGP[k * 128 + col]);
        sW[col][64 + k]  = f2bf(WlSP[k * 128 + col]);
        sW[col][128 + k] = f2bf(WrGP[k * 128 + col] + WrSP[k * 128 + col]);
    }

    int lane = threadIdx.x & 63;
    int wid  = threadIdx.x >> 6;
    int c    = lane & 15;
    int quad = lane >> 4;
    int rg   = (wid & 1) * 16;    // row offset within 32-node tile
    int cg   = (wid >> 1) * 4;    // first col-tile
    float b_c[4];
    #pragma unroll
    for (int t = 0; t < 4; t++)
        b_c[t] = bGP[(cg + t) * 16 + c] + bSP[(cg + t) * 16 + c];

    int ntiles = (N + 31) >> 5;
    for (int tile = blockIdx.x; tile < ntiles; tile += gridDim.x) {
        int base = tile << 5;
        __syncthreads();
        for (int i = threadIdx.x; i < 32 * 16; i += 256) {
            int row = i >> 4, q = (i & 15) << 2;
            int node = base + row;
            if (node < N) {
                float4 g  = *(const float4*)(aggGP + (size_t)node * 64 + q);
                float4 s  = *(const float4*)(aggSP + (size_t)node * 64 + q);
                float4 xv = *(const float4*)(x + (size_t)node * 64 + q);
                int cgn = cntGP[node], csn = cntSP[node];
                float ig = 1.0f / (float)(cgn > 1 ? cgn : 1);
                float is = 1.0f / (float)(csn > 1 ? csn : 1);
                sA[row][q + 0] = f2bf(g.x * ig);
                sA[row][q + 1] = f2bf(g.y * ig);
                sA[row][q + 2] = f2bf(g.z * ig);
                sA[row][q + 3] = f2bf(g.w * ig);
                sA[row][64 + q + 0] = f2bf(s.x * is);
                sA[row][64 + q + 1] = f2bf(s.y * is);
                sA[row][64 + q + 2] = f2bf(s.z * is);
                sA[row][64 + q + 3] = f2bf(s.w * is);
                sA[row][128 + q + 0] = f2bf(xv.x);
                sA[row][128 + q + 1] = f2bf(xv.y);
                sA[row][128 + q + 2] = f2bf(xv.z);
                sA[row][128 + q + 3] = f2bf(xv.w);
            } else {
                #pragma unroll
                for (int j = 0; j < 4; j++) {
                    sA[row][q + j] = 0;
                    sA[row][64 + q + j] = 0;
                    sA[row][128 + q + j] = 0;
                }
            }
        }
        __syncthreads();

        f32x4 acc[4] = {};
        #pragma unroll
        for (int step = 0; step < 6; step++) {
            short8 a = *(const short8*)&sA[rg + c][step * 32 + quad * 8];
            #pragma unroll
            for (int t = 0; t < 4; t++) {
                short8 bb = *(const short8*)&sW[(cg + t) * 16 + c][step * 32 + quad * 8];
                acc[t] = __builtin_amdgcn_mfma_f32_16x16x32_bf16(a, bb, acc[t], 0, 0, 0);
            }
        }

        #pragma unroll
        for (int t = 0; t < 4; t++) {
            int col = (cg + t) * 16 + c;
            #pragma unroll
            for (int r = 0; r < 4; r++) {
                int node = base + rg + quad * 4 + r;
                if (node < N) {
                    float h = fmaxf(acc[t][r] + b_c[t], 0.0f);
                    out[(size_t)node * 128 + col] = h;
                }
            }
        }
    }
}

extern "C" void kernel_launch(void* const* d_in, const int* in_sizes, int n_in,
                              void* d_out, int out_size, void* d_ws, size_t ws_size,
                              hipStream_t stream)
{
    const float* x_pfas = (const float*)d_in[0];
    const float* x_gw   = (const float*)d_in[1];
    const float* x_sw   = (const float*)d_in[2];
    const int* pg_src = (const int*)d_in[3];
    const int* pg_dst = (const int*)d_in[4];
    const int* gp_src = (const int*)d_in[5];
    const int* gp_dst = (const int*)d_in[6];
    const int* sp_src = (const int*)d_in[7];
    const int* sp_dst = (const int*)d_in[8];
    const int* ps_src = (const int*)d_in[9];
    const int* ps_dst = (const int*)d_in[10];
    const float* Wl_pg = (const float*)d_in[11];
    const float* Wr_pg = (const float*)d_in[12];
    const float* b_pg  = (const float*)d_in[13];
    const float* Wl_gp = (const float*)d_in[14];
    const float* Wr_gp = (const float*)d_in[15];
    const float* b_gp  = (const float*)d_in[16];
    const float* Wl_sp = (const float*)d_in[17];
    const float* Wr_sp = (const float*)d_in[18];
    const float* b_sp  = (const float*)d_in[19];
    const float* Wl_ps = (const float*)d_in[20];
    const float* Wr_ps = (const float*)d_in[21];
    const float* b_ps  = (const float*)d_in[22];
    const float* W_lin = (const float*)d_in[23];
    const float* b_lin = (const float*)d_in[24];
    const float* alpha = (const float*)d_in[25];

    float* out = (float*)d_out;
    float* out_pfas = out;                                 // 20000*128
    float* out_gw   = out + (size_t)N_PFAS * 128;          // 100000
    float* out_sw   = out_gw + N_GW;                       // 20000

    // Workspace layout (f32 accumulators + int counts), zeroed every call.
    float* aggGW = (float*)d_ws;                 // 100000*64 = 6,400,000
    float* aggGP = aggGW + 6400000;              // 20000*64  = 1,280,000
    float* aggSP = aggGP + 1280000;              // 1,280,000
    float* aggPS = aggSP + 1280000;              // 1,280,000
    int*   cntGW = (int*)(aggPS + 1280000);      // 100,000
    int*   cntGP = cntGW + 100000;               // 20,000
    int*   cntSP = cntGP + 20000;                // 20,000
    int*   cntPS = cntSP + 20000;                // 20,000
    size_t zero_bytes = (size_t)(6400000 + 3 * 1280000 + 160000) * 4;  // 41.6 MB
    if (zero_bytes > ws_size) zero_bytes = ws_size;
    hipMemsetAsync(d_ws, 0, zero_bytes, stream);

    int E_PG = in_sizes[3];
    int E_GP = in_sizes[5];
    int E_SP = in_sizes[7];
    int E_PS = in_sizes[9];

    auto blocks_for = [](int E) {
        long long total = (long long)E * 16;
        long long b = (total + 255) / 256;
        return (int)(b > 8192 ? 8192 : b);
    };

    scatter_kernel<<<blocks_for(E_PG), 256, 0, stream>>>(x_pfas, pg_src, pg_dst, aggGW, cntGW, E_PG);
    scatter_kernel<<<blocks_for(E_GP), 256, 0, stream>>>(x_gw,   gp_src, gp_dst, aggGP, cntGP, E_GP);
    scatter_kernel<<<blocks_for(E_SP), 256, 0, stream>>>(x_sw,   sp_src, sp_dst, aggSP, cntSP, E_SP);
    scatter_kernel<<<blocks_for(E_PS), 256, 0, stream>>>(x_pfas, ps_src, ps_dst, aggPS, cntPS, E_PS);

    head_mfma<<<512, 256, 0, stream>>>(x_gw, aggGW, cntGW, Wl_pg, Wr_pg, b_pg,
                                       W_lin, b_lin, alpha, out_gw, N_GW);
    head_mfma<<<160, 256, 0, stream>>>(x_sw, aggPS, cntPS, Wl_ps, Wr_ps, b_ps,
                                       W_lin, b_lin, alpha, out_sw, N_SW);
    pfas_mfma<<<224, 256, 0, stream>>>(x_pfas, aggGP, cntGP, aggSP, cntSP,
                                       Wl_gp, Wr_gp, b_gp, Wl_sp, Wr_sp, b_sp,
                                       out_pfas, N_PFAS);
}

// Round 4
// 1151.666 us; speedup vs baseline: 4.9228x; 3.2292x over previous
//
#include <hip/hip_runtime.h>
#include <hip/hip_bf16.h>

// Problem constants (from reference)
#define N_PFAS 20000
#define N_GW   100000
#define N_SW   20000
#define N_SEG  160000          // GW[0,100k) GP[100k,120k) SP[120k,140k) PS[140k,160k)
#define BASE_GW 0
#define BASE_GP 100000
#define BASE_SP 120000
#define BASE_PS 140000

typedef __attribute__((ext_vector_type(8))) short short8;   // 8 bf16 (4 VGPRs)
typedef __attribute__((ext_vector_type(4))) float f32x4;    // MFMA C/D frag

__device__ __forceinline__ unsigned short f2bf(float f) {
    union { float f; unsigned int u; } v;
    v.f = f;
    unsigned int u = v.u;
    unsigned int r = (u + 0x7fffu + ((u >> 16) & 1u)) >> 16;  // RNE
    return (unsigned short)r;
}

// ---------------------------------------------------------------------------
// CSR build phase 1: histogram of destination nodes (global segment ids).
// ---------------------------------------------------------------------------
__global__ void hist_kernel(const int* __restrict__ dst, int E, int base,
                            int* __restrict__ cntAll)
{
    for (int i = blockIdx.x * blockDim.x + threadIdx.x; i < E;
         i += gridDim.x * blockDim.x)
        atomicAdd(cntAll + base + dst[i], 1);
}

// ---------------------------------------------------------------------------
// CSR build phase 2: exclusive prefix scan over 160k counts, one block.
// nextAll[i] = sum(cnt[0..i)).  1024 threads x 157 elements.
// ---------------------------------------------------------------------------
__global__ void __launch_bounds__(1024)
scan_kernel(const int* __restrict__ cntAll, int* __restrict__ nextAll, int n)
{
    const int CH = 157;  // 1024*157 = 160768 >= 160000
    int t = threadIdx.x;
    int s0 = t * CH;
    int sum = 0;
    for (int i = 0; i < CH; i++) {
        int idx = s0 + i;
        if (idx < n) sum += cntAll[idx];
    }
    __shared__ int lds[1024];
    lds[t] = sum;
    __syncthreads();
    // Hillis-Steele inclusive scan
    for (int off = 1; off < 1024; off <<= 1) {
        int v = (t >= off) ? lds[t - off] : 0;
        __syncthreads();
        lds[t] += v;
        __syncthreads();
    }
    int run = lds[t] - sum;  // exclusive base for this thread's chunk
    for (int i = 0; i < CH; i++) {
        int idx = s0 + i;
        if (idx < n) {
            int c = cntAll[idx];
            nextAll[idx] = run;
            run += c;
        }
    }
}

// ---------------------------------------------------------------------------
// CSR build phase 3: bucket src ids by destination. nextAll ends at CSR end.
// ---------------------------------------------------------------------------
__global__ void fill_kernel(const int* __restrict__ src, const int* __restrict__ dst,
                            int E, int base, int* __restrict__ nextAll,
                            int* __restrict__ edge_src)
{
    for (int i = blockIdx.x * blockDim.x + threadIdx.x; i < E;
         i += gridDim.x * blockDim.x) {
        int slot = atomicAdd(nextAll + base + dst[i], 1);
        edge_src[slot] = src[i];
    }
}

// ---------------------------------------------------------------------------
// Pull aggregation: one wave per (relation,node); lane = feature.
// Gathers coalesced 256B rows, accumulates f32, writes bf16 MEAN.
// ---------------------------------------------------------------------------
__global__ void __launch_bounds__(256)
agg_kernel(const float* __restrict__ xp, const float* __restrict__ xg,
           const float* __restrict__ xs,
           const int* __restrict__ cntAll, const int* __restrict__ nextAll,
           const int* __restrict__ edge_src, unsigned short* __restrict__ meanAll)
{
    int wid = (blockIdx.x * blockDim.x + threadIdx.x) >> 6;
    int lane = threadIdx.x & 63;
    if (wid >= N_SEG) return;
    const float* x = (wid < BASE_GP) ? xp
                   : (wid < BASE_SP) ? xg
                   : (wid < BASE_PS) ? xs : xp;
    int cnt = cntAll[wid];
    int end = nextAll[wid];      // after fill: start + cnt
    int j = end - cnt;
    float acc = 0.0f;
    while (j + 64 <= end) {
        int ev = edge_src[j + lane] << 6;  // element offset of row
        #pragma unroll 16
        for (int t = 0; t < 64; t++) {
            int off = __shfl(ev, t);
            acc += x[off + lane];
        }
        j += 64;
    }
    if (j < end) {
        int take = end - j;
        int ev = (lane < take) ? (edge_src[j + lane] << 6) : 0;
        for (int t = 0; t < take; t++) {
            int off = __shfl(ev, t);
            acc += x[off + lane];
        }
    }
    float inv = 1.0f / (float)(cnt > 1 ? cnt : 1);
    meanAll[(size_t)wid * 64 + lane] = f2bf(acc * inv);
}

// ---------------------------------------------------------------------------
// GW / SW nodes via MFMA: C[64 nodes x 128] = [mean|x] @ [Wl;Wr] + b,
// fused relu + W_lin dot + prelu -> out[node] (scalar).
// mean arrives as bf16 (already divided).
// ---------------------------------------------------------------------------
__global__ void __launch_bounds__(256)
head_mfma(const float* __restrict__ x, const unsigned short* __restrict__ mean,
          const float* __restrict__ Wl, const float* __restrict__ Wr,
          const float* __restrict__ b, const float* __restrict__ Wlin,
          const float* __restrict__ b_lin, const float* __restrict__ alpha,
          float* __restrict__ out, int N)
{
    __shared__ __align__(16) unsigned short sW[128][136];
    __shared__ __align__(16) unsigned short sA[64][136];

    for (int i = threadIdx.x; i < 64 * 128; i += 256) {
        int k = i >> 7, col = i & 127;
        sW[col][k]      = f2bf(Wl[k * 128 + col]);
        sW[col][64 + k] = f2bf(Wr[k * 128 + col]);
    }

    int lane = threadIdx.x & 63;
    int wid  = threadIdx.x >> 6;
    int c    = lane & 15;
    int quad = lane >> 4;
    float wl_c[8], b_c[8];
    #pragma unroll
    for (int t = 0; t < 8; t++) {
        wl_c[t] = Wlin[t * 16 + c];
        b_c[t]  = b[t * 16 + c];
    }
    float blin = b_lin[0], al = alpha[0];

    int ntiles = (N + 63) >> 6;
    for (int tile = blockIdx.x; tile < ntiles; tile += gridDim.x) {
        int base = tile << 6;
        __syncthreads();
        for (int i = threadIdx.x; i < 64 * 16; i += 256) {
            int row = i >> 4, q = (i & 15) << 2;
            int node = base + row;
            if (node < N) {
                ushort4 mv = *(const ushort4*)(mean + (size_t)node * 64 + q);
                float4  xv = *(const float4*)(x + (size_t)node * 64 + q);
                sA[row][q + 0] = mv.x;
                sA[row][q + 1] = mv.y;
                sA[row][q + 2] = mv.z;
                sA[row][q + 3] = mv.w;
                sA[row][64 + q + 0] = f2bf(xv.x);
                sA[row][64 + q + 1] = f2bf(xv.y);
                sA[row][64 + q + 2] = f2bf(xv.z);
                sA[row][64 + q + 3] = f2bf(xv.w);
            } else {
                #pragma unroll
                for (int j = 0; j < 4; j++) {
                    sA[row][q + j] = 0;
                    sA[row][64 + q + j] = 0;
                }
            }
        }
        __syncthreads();

        f32x4 acc[8] = {};
        #pragma unroll
        for (int step = 0; step < 4; step++) {
            short8 a = *(const short8*)&sA[wid * 16 + c][step * 32 + quad * 8];
            #pragma unroll
            for (int t = 0; t < 8; t++) {
                short8 bb = *(const short8*)&sW[t * 16 + c][step * 32 + quad * 8];
                acc[t] = __builtin_amdgcn_mfma_f32_16x16x32_bf16(a, bb, acc[t], 0, 0, 0);
            }
        }

        float p[4] = {0.f, 0.f, 0.f, 0.f};
        #pragma unroll
        for (int t = 0; t < 8; t++) {
            #pragma unroll
            for (int r = 0; r < 4; r++) {
                float h = fmaxf(acc[t][r] + b_c[t], 0.0f);
                p[r] += h * wl_c[t];
            }
        }
        #pragma unroll
        for (int m = 1; m < 16; m <<= 1) {
            #pragma unroll
            for (int r = 0; r < 4; r++) p[r] += __shfl_xor(p[r], m);
        }
        if (c == 0) {
            #pragma unroll
            for (int r = 0; r < 4; r++) {
                int node = base + wid * 16 + quad * 4 + r;
                if (node < N) {
                    float y = p[r] + blin;
                    out[node] = y > 0.0f ? y : al * y;
                }
            }
        }
    }
}

// ---------------------------------------------------------------------------
// PFAS nodes via MFMA: C[32 x 128] = [mean_gp|mean_sp|x] @ [WlGP;WlSP;Wr_sum]
// + b_sum, relu, direct 128-wide store. Means arrive as bf16.
// ---------------------------------------------------------------------------
__global__ void __launch_bounds__(256)
pfas_mfma(const float* __restrict__ x,
          const unsigned short* __restrict__ meanGP,
          const unsigned short* __restrict__ meanSP,
          const float* __restrict__ WlGP, const float* __restrict__ WrGP,
          const float* __restrict__ bGP,
          const float* __restrict__ WlSP, const float* __restrict__ WrSP,
          const float* __restrict__ bSP,
          float* __restrict__ out, int N)
{
    __shared__ __align__(16) unsigned short sW[128][200];
    __shared__ __align__(16) unsigned short sA[32][200];

    for (int i = threadIdx.x; i < 64 * 128; i += 256) {
        int k = i >> 7, col = i & 127;
        sW[col][k]       = f2bf(WlGP[k * 128 + col]);
        sW[col][64 + k]  = f2bf(WlSP[k * 128 + col]);
        sW[col][128 + k] = f2bf(WrGP[k * 128 + col] + WrSP[k * 128 + col]);
    }

    int lane = threadIdx.x & 63;
    int wid  = threadIdx.x >> 6;
    int c    = lane & 15;
    int quad = lane >> 4;
    int rg   = (wid & 1) * 16;
    int cg   = (wid >> 1) * 4;
    float b_c[4];
    #pragma unroll
    for (int t = 0; t < 4; t++)
        b_c[t] = bGP[(cg + t) * 16 + c] + bSP[(cg + t) * 16 + c];

    int ntiles = (N + 31) >> 5;
    for (int tile = blockIdx.x; tile < ntiles; tile += gridDim.x) {
        int base = tile << 5;
        __syncthreads();
        for (int i = threadIdx.x; i < 32 * 16; i += 256) {
            int row = i >> 4, q = (i & 15) << 2;
            int node = base + row;
            if (node < N) {
                ushort4 g  = *(const ushort4*)(meanGP + (size_t)node * 64 + q);
                ushort4 s  = *(const ushort4*)(meanSP + (size_t)node * 64 + q);
                float4  xv = *(const float4*)(x + (size_t)node * 64 + q);
                sA[row][q + 0] = g.x;  sA[row][q + 1] = g.y;
                sA[row][q + 2] = g.z;  sA[row][q + 3] = g.w;
                sA[row][64 + q + 0] = s.x;  sA[row][64 + q + 1] = s.y;
                sA[row][64 + q + 2] = s.z;  sA[row][64 + q + 3] = s.w;
                sA[row][128 + q + 0] = f2bf(xv.x);
                sA[row][128 + q + 1] = f2bf(xv.y);
                sA[row][128 + q + 2] = f2bf(xv.z);
                sA[row][128 + q + 3] = f2bf(xv.w);
            } else {
                #pragma unroll
                for (int j = 0; j < 4; j++) {
                    sA[row][q + j] = 0;
                    sA[row][64 + q + j] = 0;
                    sA[row][128 + q + j] = 0;
                }
            }
        }
        __syncthreads();

        f32x4 acc[4] = {};
        #pragma unroll
        for (int step = 0; step < 6; step++) {
            short8 a = *(const short8*)&sA[rg + c][step * 32 + quad * 8];
            #pragma unroll
            for (int t = 0; t < 4; t++) {
                short8 bb = *(const short8*)&sW[(cg + t) * 16 + c][step * 32 + quad * 8];
                acc[t] = __builtin_amdgcn_mfma_f32_16x16x32_bf16(a, bb, acc[t], 0, 0, 0);
            }
        }

        #pragma unroll
        for (int t = 0; t < 4; t++) {
            int col = (cg + t) * 16 + c;
            #pragma unroll
            for (int r = 0; r < 4; r++) {
                int node = base + rg + quad * 4 + r;
                if (node < N) {
                    float h = fmaxf(acc[t][r] + b_c[t], 0.0f);
                    out[(size_t)node * 128 + col] = h;
                }
            }
        }
    }
}

extern "C" void kernel_launch(void* const* d_in, const int* in_sizes, int n_in,
                              void* d_out, int out_size, void* d_ws, size_t ws_size,
                              hipStream_t stream)
{
    const float* x_pfas = (const float*)d_in[0];
    const float* x_gw   = (const float*)d_in[1];
    const float* x_sw   = (const float*)d_in[2];
    const int* pg_src = (const int*)d_in[3];
    const int* pg_dst = (const int*)d_in[4];
    const int* gp_src = (const int*)d_in[5];
    const int* gp_dst = (const int*)d_in[6];
    const int* sp_src = (const int*)d_in[7];
    const int* sp_dst = (const int*)d_in[8];
    const int* ps_src = (const int*)d_in[9];
    const int* ps_dst = (const int*)d_in[10];
    const float* Wl_pg = (const float*)d_in[11];
    const float* Wr_pg = (const float*)d_in[12];
    const float* b_pg  = (const float*)d_in[13];
    const float* Wl_gp = (const float*)d_in[14];
    const float* Wr_gp = (const float*)d_in[15];
    const float* b_gp  = (const float*)d_in[16];
    const float* Wl_sp = (const float*)d_in[17];
    const float* Wr_sp = (const float*)d_in[18];
    const float* b_sp  = (const float*)d_in[19];
    const float* Wl_ps = (const float*)d_in[20];
    const float* Wr_ps = (const float*)d_in[21];
    const float* b_ps  = (const float*)d_in[22];
    const float* W_lin = (const float*)d_in[23];
    const float* b_lin = (const float*)d_in[24];
    const float* alpha = (const float*)d_in[25];

    float* out = (float*)d_out;
    float* out_pfas = out;                                 // 20000*128
    float* out_gw   = out + (size_t)N_PFAS * 128;          // 100000
    float* out_sw   = out_gw + N_GW;                       // 20000

    int E_PG = in_sizes[3];
    int E_GP = in_sizes[5];
    int E_SP = in_sizes[7];
    int E_PS = in_sizes[9];
    int E_total = E_PG + E_GP + E_SP + E_PS;               // 4,000,000

    // Workspace layout: bf16 means (by segment) + counters + CSR edge array.
    unsigned short* meanAll = (unsigned short*)d_ws;       // 160000*64 bf16 = 20.48 MB
    unsigned short* meanGW = meanAll + (size_t)BASE_GW * 64;
    unsigned short* meanGP = meanAll + (size_t)BASE_GP * 64;
    unsigned short* meanSP = meanAll + (size_t)BASE_SP * 64;
    unsigned short* meanPS = meanAll + (size_t)BASE_PS * 64;
    int* cntAll  = (int*)(meanAll + (size_t)N_SEG * 64);   // 160000 ints
    int* nextAll = cntAll + N_SEG;                         // 160000 ints
    int* edge_src = nextAll + N_SEG;                       // E_total ints (16 MB)

    // Zero only the histogram counters (640 KB).
    hipMemsetAsync(cntAll, 0, (size_t)N_SEG * sizeof(int), stream);

    auto blocks_for = [](int E) {
        int b = (E + 255) / 256;
        return b > 8192 ? 8192 : b;
    };

    hist_kernel<<<blocks_for(E_PG), 256, 0, stream>>>(pg_dst, E_PG, BASE_GW, cntAll);
    hist_kernel<<<blocks_for(E_GP), 256, 0, stream>>>(gp_dst, E_GP, BASE_GP, cntAll);
    hist_kernel<<<blocks_for(E_SP), 256, 0, stream>>>(sp_dst, E_SP, BASE_SP, cntAll);
    hist_kernel<<<blocks_for(E_PS), 256, 0, stream>>>(ps_dst, E_PS, BASE_PS, cntAll);

    scan_kernel<<<1, 1024, 0, stream>>>(cntAll, nextAll, N_SEG);

    fill_kernel<<<blocks_for(E_PG), 256, 0, stream>>>(pg_src, pg_dst, E_PG, BASE_GW, nextAll, edge_src);
    fill_kernel<<<blocks_for(E_GP), 256, 0, stream>>>(gp_src, gp_dst, E_GP, BASE_GP, nextAll, edge_src);
    fill_kernel<<<blocks_for(E_SP), 256, 0, stream>>>(sp_src, sp_dst, E_SP, BASE_SP, nextAll, edge_src);
    fill_kernel<<<blocks_for(E_PS), 256, 0, stream>>>(ps_src, ps_dst, E_PS, BASE_PS, nextAll, edge_src);

    agg_kernel<<<(N_SEG + 3) / 4, 256, 0, stream>>>(x_pfas, x_gw, x_sw,
                                                    cntAll, nextAll, edge_src, meanAll);

    head_mfma<<<512, 256, 0, stream>>>(x_gw, meanGW, Wl_pg, Wr_pg, b_pg,
                                       W_lin, b_lin, alpha, out_gw, N_GW);
    head_mfma<<<160, 256, 0, stream>>>(x_sw, meanPS, Wl_ps, Wr_ps, b_ps,
                                       W_lin, b_lin, alpha, out_sw, N_SW);
    pfas_mfma<<<224, 256, 0, stream>>>(x_pfas, meanGP, meanSP,
                                       Wl_gp, Wr_gp, b_gp, Wl_sp, Wr_sp, b_sp,
                                       out_pfas, N_PFAS);
}

// Round 5
// 866.689 us; speedup vs baseline: 6.5414x; 1.3288x over previous
//
#include <hip/hip_runtime.h>
#include <hip/hip_bf16.h>

// Problem constants (from reference)
#define N_PFAS 20000
#define N_GW   100000
#define N_SW   20000
#define N_SEG  160000          // GW[0,100k) GP[100k,120k) SP[120k,140k) PS[140k,160k)
#define BASE_GW 0
#define BASE_GP 100000
#define BASE_SP 120000
#define BASE_PS 140000

typedef __attribute__((ext_vector_type(8))) short short8;   // 8 bf16 (4 VGPRs)
typedef __attribute__((ext_vector_type(4))) float f32x4;    // MFMA C/D frag

__device__ __forceinline__ unsigned short f2bf(float f) {
    union { float f; unsigned int u; } v;
    v.f = f;
    unsigned int u = v.u;
    unsigned int r = (u + 0x7fffu + ((u >> 16) & 1u)) >> 16;  // RNE
    return (unsigned short)r;
}

// ---------------------------------------------------------------------------
// CSR build phase 1: histogram of destination nodes, all 4 relations fused.
// ---------------------------------------------------------------------------
__global__ void hist4_kernel(const int* __restrict__ d0, int E0,
                             const int* __restrict__ d1, int E1,
                             const int* __restrict__ d2, int E2,
                             const int* __restrict__ d3, int E3,
                             int* __restrict__ cntAll)
{
    int total = E0 + E1 + E2 + E3;
    for (int i = blockIdx.x * blockDim.x + threadIdx.x; i < total;
         i += gridDim.x * blockDim.x) {
        int g;
        if (i < E0)                g = BASE_GW + d0[i];
        else if (i < E0 + E1)      g = BASE_GP + d1[i - E0];
        else if (i < E0 + E1 + E2) g = BASE_SP + d2[i - E0 - E1];
        else                       g = BASE_PS + d3[i - E0 - E1 - E2];
        atomicAdd(cntAll + g, 1);
    }
}

// ---------------------------------------------------------------------------
// CSR build phase 2: hierarchical exclusive scan over 160k counts.
// ---------------------------------------------------------------------------
__global__ void __launch_bounds__(256)
scan_part(const int* __restrict__ cnt, int* __restrict__ next,
          int* __restrict__ partials, int n)
{
    __shared__ int lds[256];
    int i = blockIdx.x * 256 + threadIdx.x;
    int v = (i < n) ? cnt[i] : 0;
    lds[threadIdx.x] = v;
    __syncthreads();
    #pragma unroll
    for (int off = 1; off < 256; off <<= 1) {
        int t = (threadIdx.x >= off) ? lds[threadIdx.x - off] : 0;
        __syncthreads();
        lds[threadIdx.x] += t;
        __syncthreads();
    }
    if (i < n) next[i] = lds[threadIdx.x] - v;   // block-local exclusive
    if (threadIdx.x == 255) partials[blockIdx.x] = lds[255];
}

__global__ void __launch_bounds__(1024)
scan_tops(int* __restrict__ partials, int nb)
{
    __shared__ int lds[1024];
    int t = threadIdx.x;
    int v = (t < nb) ? partials[t] : 0;
    lds[t] = v;
    __syncthreads();
    #pragma unroll
    for (int off = 1; off < 1024; off <<= 1) {
        int x = (t >= off) ? lds[t - off] : 0;
        __syncthreads();
        lds[t] += x;
        __syncthreads();
    }
    if (t < nb) partials[t] = lds[t] - v;        // exclusive block offsets
}

__global__ void __launch_bounds__(256)
scan_add(int* __restrict__ next, const int* __restrict__ partials, int n)
{
    int i = blockIdx.x * 256 + threadIdx.x;
    if (i < n) next[i] += partials[blockIdx.x];
}

// ---------------------------------------------------------------------------
// CSR build phase 3: bucket src ids by destination, all 4 relations fused.
// nextAll[g] ends at CSR range end (start + cnt).
// ---------------------------------------------------------------------------
__global__ void fill4_kernel(const int* __restrict__ s0, const int* __restrict__ d0, int E0,
                             const int* __restrict__ s1, const int* __restrict__ d1, int E1,
                             const int* __restrict__ s2, const int* __restrict__ d2, int E2,
                             const int* __restrict__ s3, const int* __restrict__ d3, int E3,
                             int* __restrict__ nextAll, int* __restrict__ edge_src)
{
    int total = E0 + E1 + E2 + E3;
    for (int i = blockIdx.x * blockDim.x + threadIdx.x; i < total;
         i += gridDim.x * blockDim.x) {
        int g, s;
        if (i < E0)                { g = BASE_GW + d0[i];           s = s0[i]; }
        else if (i < E0 + E1)      { int j = i - E0;       g = BASE_GP + d1[j]; s = s1[j]; }
        else if (i < E0 + E1 + E2) { int j = i - E0 - E1;  g = BASE_SP + d2[j]; s = s2[j]; }
        else                       { int j = i - E0 - E1 - E2; g = BASE_PS + d3[j]; s = s3[j]; }
        int slot = atomicAdd(nextAll + g, 1);
        edge_src[slot] = s;
    }
}

// ---------------------------------------------------------------------------
// Pull aggregation: one wave per (relation,node); lane = feature.
// Gathers coalesced 256B rows, accumulates f32, writes bf16 MEAN.
// ---------------------------------------------------------------------------
__global__ void __launch_bounds__(256)
agg_kernel(const float* __restrict__ xp, const float* __restrict__ xg,
           const float* __restrict__ xs,
           const int* __restrict__ cntAll, const int* __restrict__ nextAll,
           const int* __restrict__ edge_src, unsigned short* __restrict__ meanAll)
{
    int wid = (blockIdx.x * blockDim.x + threadIdx.x) >> 6;
    int lane = threadIdx.x & 63;
    if (wid >= N_SEG) return;
    const float* x = (wid < BASE_GP) ? xp
                   : (wid < BASE_SP) ? xg
                   : (wid < BASE_PS) ? xs : xp;
    int cnt = cntAll[wid];
    int end = nextAll[wid];      // after fill: start + cnt
    int j = end - cnt;
    float acc = 0.0f;
    while (j + 64 <= end) {
        int ev = edge_src[j + lane] << 6;  // element offset of row
        #pragma unroll 16
        for (int t = 0; t < 64; t++) {
            int off = __shfl(ev, t);
            acc += x[off + lane];
        }
        j += 64;
    }
    if (j < end) {
        int take = end - j;
        int ev = (lane < take) ? (edge_src[j + lane] << 6) : 0;
        for (int t = 0; t < take; t++) {
            int off = __shfl(ev, t);
            acc += x[off + lane];
        }
    }
    float inv = 1.0f / (float)(cnt > 1 ? cnt : 1);
    meanAll[(size_t)wid * 64 + lane] = f2bf(acc * inv);
}

// ---------------------------------------------------------------------------
// GW / SW nodes via MFMA: C[64 nodes x 128] = [mean|x] @ [Wl;Wr] + b,
// fused relu + W_lin dot + prelu -> out[node] (scalar).
// ---------------------------------------------------------------------------
__global__ void __launch_bounds__(256)
head_mfma(const float* __restrict__ x, const unsigned short* __restrict__ mean,
          const float* __restrict__ Wl, const float* __restrict__ Wr,
          const float* __restrict__ b, const float* __restrict__ Wlin,
          const float* __restrict__ b_lin, const float* __restrict__ alpha,
          float* __restrict__ out, int N)
{
    __shared__ __align__(16) unsigned short sW[128][136];
    __shared__ __align__(16) unsigned short sA[64][136];

    for (int i = threadIdx.x; i < 64 * 128; i += 256) {
        int k = i >> 7, col = i & 127;
        sW[col][k]      = f2bf(Wl[k * 128 + col]);
        sW[col][64 + k] = f2bf(Wr[k * 128 + col]);
    }

    int lane = threadIdx.x & 63;
    int wid  = threadIdx.x >> 6;
    int c    = lane & 15;
    int quad = lane >> 4;
    float wl_c[8], b_c[8];
    #pragma unroll
    for (int t = 0; t < 8; t++) {
        wl_c[t] = Wlin[t * 16 + c];
        b_c[t]  = b[t * 16 + c];
    }
    float blin = b_lin[0], al = alpha[0];

    int ntiles = (N + 63) >> 6;
    for (int tile = blockIdx.x; tile < ntiles; tile += gridDim.x) {
        int base = tile << 6;
        __syncthreads();
        for (int i = threadIdx.x; i < 64 * 16; i += 256) {
            int row = i >> 4, q = (i & 15) << 2;
            int node = base + row;
            if (node < N) {
                ushort4 mv = *(const ushort4*)(mean + (size_t)node * 64 + q);
                float4  xv = *(const float4*)(x + (size_t)node * 64 + q);
                sA[row][q + 0] = mv.x;
                sA[row][q + 1] = mv.y;
                sA[row][q + 2] = mv.z;
                sA[row][q + 3] = mv.w;
                sA[row][64 + q + 0] = f2bf(xv.x);
                sA[row][64 + q + 1] = f2bf(xv.y);
                sA[row][64 + q + 2] = f2bf(xv.z);
                sA[row][64 + q + 3] = f2bf(xv.w);
            } else {
                #pragma unroll
                for (int j = 0; j < 4; j++) {
                    sA[row][q + j] = 0;
                    sA[row][64 + q + j] = 0;
                }
            }
        }
        __syncthreads();

        f32x4 acc[8] = {};
        #pragma unroll
        for (int step = 0; step < 4; step++) {
            short8 a = *(const short8*)&sA[wid * 16 + c][step * 32 + quad * 8];
            #pragma unroll
            for (int t = 0; t < 8; t++) {
                short8 bb = *(const short8*)&sW[t * 16 + c][step * 32 + quad * 8];
                acc[t] = __builtin_amdgcn_mfma_f32_16x16x32_bf16(a, bb, acc[t], 0, 0, 0);
            }
        }

        float p[4] = {0.f, 0.f, 0.f, 0.f};
        #pragma unroll
        for (int t = 0; t < 8; t++) {
            #pragma unroll
            for (int r = 0; r < 4; r++) {
                float h = fmaxf(acc[t][r] + b_c[t], 0.0f);
                p[r] += h * wl_c[t];
            }
        }
        #pragma unroll
        for (int m = 1; m < 16; m <<= 1) {
            #pragma unroll
            for (int r = 0; r < 4; r++) p[r] += __shfl_xor(p[r], m);
        }
        if (c == 0) {
            #pragma unroll
            for (int r = 0; r < 4; r++) {
                int node = base + wid * 16 + quad * 4 + r;
                if (node < N) {
                    float y = p[r] + blin;
                    out[node] = y > 0.0f ? y : al * y;
                }
            }
        }
    }
}

// ---------------------------------------------------------------------------
// PFAS nodes via MFMA: C[32 x 128] = [mean_gp|mean_sp|x] @ [WlGP;WlSP;Wr_sum]
// + b_sum, relu, direct 128-wide store.
// ---------------------------------------------------------------------------
__global__ void __launch_bounds__(256)
pfas_mfma(const float* __restrict__ x,
          const unsigned short* __restrict__ meanGP,
          const unsigned short* __restrict__ meanSP,
          const float* __restrict__ WlGP, const float* __restrict__ WrGP,
          const float* __restrict__ bGP,
          const float* __restrict__ WlSP, const float* __restrict__ WrSP,
          const float* __restrict__ bSP,
          float* __restrict__ out, int N)
{
    __shared__ __align__(16) unsigned short sW[128][200];
    __shared__ __align__(16) unsigned short sA[32][200];

    for (int i = threadIdx.x; i < 64 * 128; i += 256) {
        int k = i >> 7, col = i & 127;
        sW[col][k]       = f2bf(WlGP[k * 128 + col]);
        sW[col][64 + k]  = f2bf(WlSP[k * 128 + col]);
        sW[col][128 + k] = f2bf(WrGP[k * 128 + col] + WrSP[k * 128 + col]);
    }

    int lane = threadIdx.x & 63;
    int wid  = threadIdx.x >> 6;
    int c    = lane & 15;
    int quad = lane >> 4;
    int rg   = (wid & 1) * 16;
    int cg   = (wid >> 1) * 4;
    float b_c[4];
    #pragma unroll
    for (int t = 0; t < 4; t++)
        b_c[t] = bGP[(cg + t) * 16 + c] + bSP[(cg + t) * 16 + c];

    int ntiles = (N + 31) >> 5;
    for (int tile = blockIdx.x; tile < ntiles; tile += gridDim.x) {
        int base = tile << 5;
        __syncthreads();
        for (int i = threadIdx.x; i < 32 * 16; i += 256) {
            int row = i >> 4, q = (i & 15) << 2;
            int node = base + row;
            if (node < N) {
                ushort4 g  = *(const ushort4*)(meanGP + (size_t)node * 64 + q);
                ushort4 s  = *(const ushort4*)(meanSP + (size_t)node * 64 + q);
                float4  xv = *(const float4*)(x + (size_t)node * 64 + q);
                sA[row][q + 0] = g.x;  sA[row][q + 1] = g.y;
                sA[row][q + 2] = g.z;  sA[row][q + 3] = g.w;
                sA[row][64 + q + 0] = s.x;  sA[row][64 + q + 1] = s.y;
                sA[row][64 + q + 2] = s.z;  sA[row][64 + q + 3] = s.w;
                sA[row][128 + q + 0] = f2bf(xv.x);
                sA[row][128 + q + 1] = f2bf(xv.y);
                sA[row][128 + q + 2] = f2bf(xv.z);
                sA[row][128 + q + 3] = f2bf(xv.w);
            } else {
                #pragma unroll
                for (int j = 0; j < 4; j++) {
                    sA[row][q + j] = 0;
                    sA[row][64 + q + j] = 0;
                    sA[row][128 + q + j] = 0;
                }
            }
        }
        __syncthreads();

        f32x4 acc[4] = {};
        #pragma unroll
        for (int step = 0; step < 6; step++) {
            short8 a = *(const short8*)&sA[rg + c][step * 32 + quad * 8];
            #pragma unroll
            for (int t = 0; t < 4; t++) {
                short8 bb = *(const short8*)&sW[(cg + t) * 16 + c][step * 32 + quad * 8];
                acc[t] = __builtin_amdgcn_mfma_f32_16x16x32_bf16(a, bb, acc[t], 0, 0, 0);
            }
        }

        #pragma unroll
        for (int t = 0; t < 4; t++) {
            int col = (cg + t) * 16 + c;
            #pragma unroll
            for (int r = 0; r < 4; r++) {
                int node = base + rg + quad * 4 + r;
                if (node < N) {
                    float h = fmaxf(acc[t][r] + b_c[t], 0.0f);
                    out[(size_t)node * 128 + col] = h;
                }
            }
        }
    }
}

extern "C" void kernel_launch(void* const* d_in, const int* in_sizes, int n_in,
                              void* d_out, int out_size, void* d_ws, size_t ws_size,
                              hipStream_t stream)
{
    const float* x_pfas = (const float*)d_in[0];
    const float* x_gw   = (const float*)d_in[1];
    const float* x_sw   = (const float*)d_in[2];
    const int* pg_src = (const int*)d_in[3];
    const int* pg_dst = (const int*)d_in[4];
    const int* gp_src = (const int*)d_in[5];
    const int* gp_dst = (const int*)d_in[6];
    const int* sp_src = (const int*)d_in[7];
    const int* sp_dst = (const int*)d_in[8];
    const int* ps_src = (const int*)d_in[9];
    const int* ps_dst = (const int*)d_in[10];
    const float* Wl_pg = (const float*)d_in[11];
    const float* Wr_pg = (const float*)d_in[12];
    const float* b_pg  = (const float*)d_in[13];
    const float* Wl_gp = (const float*)d_in[14];
    const float* Wr_gp = (const float*)d_in[15];
    const float* b_gp  = (const float*)d_in[16];
    const float* Wl_sp = (const float*)d_in[17];
    const float* Wr_sp = (const float*)d_in[18];
    const float* b_sp  = (const float*)d_in[19];
    const float* Wl_ps = (const float*)d_in[20];
    const float* Wr_ps = (const float*)d_in[21];
    const float* b_ps  = (const float*)d_in[22];
    const float* W_lin = (const float*)d_in[23];
    const float* b_lin = (const float*)d_in[24];
    const float* alpha = (const float*)d_in[25];

    float* out = (float*)d_out;
    float* out_pfas = out;                                 // 20000*128
    float* out_gw   = out + (size_t)N_PFAS * 128;          // 100000
    float* out_sw   = out_gw + N_GW;                       // 20000

    int E_PG = in_sizes[3];
    int E_GP = in_sizes[5];
    int E_SP = in_sizes[7];
    int E_PS = in_sizes[9];
    int E_total = E_PG + E_GP + E_SP + E_PS;               // 4,000,000

    // Workspace layout: bf16 means + counters + CSR edge array + scan partials.
    unsigned short* meanAll = (unsigned short*)d_ws;       // 160000*64 bf16 = 20.48 MB
    unsigned short* meanGW = meanAll + (size_t)BASE_GW * 64;
    unsigned short* meanGP = meanAll + (size_t)BASE_GP * 64;
    unsigned short* meanSP = meanAll + (size_t)BASE_SP * 64;
    unsigned short* meanPS = meanAll + (size_t)BASE_PS * 64;
    int* cntAll  = (int*)(meanAll + (size_t)N_SEG * 64);   // 160000 ints
    int* nextAll = cntAll + N_SEG;                         // 160000 ints
    int* edge_src = nextAll + N_SEG;                       // E_total ints (16 MB)
    int* partials = edge_src + E_total;                    // 625 ints

    // Zero only the histogram counters (640 KB).
    hipMemsetAsync(cntAll, 0, (size_t)N_SEG * sizeof(int), stream);

    const int SCAN_NB = (N_SEG + 255) / 256;               // 625

    hist4_kernel<<<4096, 256, 0, stream>>>(pg_dst, E_PG, gp_dst, E_GP,
                                           sp_dst, E_SP, ps_dst, E_PS, cntAll);

    scan_part<<<SCAN_NB, 256, 0, stream>>>(cntAll, nextAll, partials, N_SEG);
    scan_tops<<<1, 1024, 0, stream>>>(partials, SCAN_NB);
    scan_add<<<SCAN_NB, 256, 0, stream>>>(nextAll, partials, N_SEG);

    fill4_kernel<<<4096, 256, 0, stream>>>(pg_src, pg_dst, E_PG,
                                           gp_src, gp_dst, E_GP,
                                           sp_src, sp_dst, E_SP,
                                           ps_src, ps_dst, E_PS,
                                           nextAll, edge_src);

    agg_kernel<<<(N_SEG + 3) / 4, 256, 0, stream>>>(x_pfas, x_gw, x_sw,
                                                    cntAll, nextAll, edge_src, meanAll);

    head_mfma<<<512, 256, 0, stream>>>(x_gw, meanGW, Wl_pg, Wr_pg, b_pg,
                                       W_lin, b_lin, alpha, out_gw, N_GW);
    head_mfma<<<160, 256, 0, stream>>>(x_sw, meanPS, Wl_ps, Wr_ps, b_ps,
                                       W_lin, b_lin, alpha, out_sw, N_SW);
    pfas_mfma<<<224, 256, 0, stream>>>(x_pfas, meanGP, meanSP,
                                       Wl_gp, Wr_gp, b_gp, Wl_sp, Wr_sp, b_sp,
                                       out_pfas, N_PFAS);
}